// Round 1
// baseline (1048.132 us; speedup 1.0000x reference)
//
#include <hip/hip_runtime.h>

#define N_NODES 100000
#define N_EDGES 800000
#define DF 64
#define NGRAPH 512
#define LDIM 192   // L * D

// ---------------------------------------------------------------------------
// Edge scatter: agg[row[e]] += h[col[e]]  (one thread per (edge, feature))
// ---------------------------------------------------------------------------
__global__ __launch_bounds__(256) void scatter_kernel(
    const float* __restrict__ h,
    const int* __restrict__ ei,   // [2, E]
    float* __restrict__ agg)
{
    int idx = blockIdx.x * blockDim.x + threadIdx.x;
    int e = idx >> 6;
    int f = idx & 63;
    if (e >= N_EDGES) return;
    int r = ei[e];
    int c = ei[N_EDGES + e];
    unsafeAtomicAdd(&agg[r * DF + f], h[c * DF + f]);
}

// ---------------------------------------------------------------------------
// Fused GIN MLP: z = (1+eps)*h + agg; z1 = relu(z@W1+b1); z2 = relu(z1@W2+b2);
// z3 = relu(z2 + gin_bias). Writes z3 in-place over agg. Accumulates per-
// feature sum and sumsq (double) for the following BatchNorm.
// ---------------------------------------------------------------------------
__global__ __launch_bounds__(256) void mlp_kernel(
    const float* __restrict__ h,
    float* __restrict__ z,              // agg in / z3 out
    const float* __restrict__ W1,       // [64,64] layer slice
    const float* __restrict__ b1,
    const float* __restrict__ W2,
    const float* __restrict__ b2,
    const float* __restrict__ gin_eps,  // scalar
    const float* __restrict__ gin_bias,
    double* __restrict__ stats)         // [128]: sum[64], sumsq[64]
{
    __shared__ float W1s[64 * 64];
    __shared__ float W2s[64 * 64];
    __shared__ float zs[4][64];
    __shared__ float z1s[4][64];
    __shared__ double red[2][4][64];

    int tid = threadIdx.x;
    for (int i = tid; i < 4096; i += 256) {
        W1s[i] = W1[i];
        W2s[i] = W2[i];
    }

    int n = tid >> 6;   // 0..3 (wave id; one node per wave)
    int f = tid & 63;
    float b1f = b1[f];
    float b2f = b2[f];
    float gbf = gin_bias[f];
    float epsf = 1.0f + gin_eps[0];
    double lsum = 0.0, lsq = 0.0;
    __syncthreads();

    const int ntiles = N_NODES / 4;   // 25000, N divisible by 4
    for (int tile = blockIdx.x; tile < ntiles; tile += gridDim.x) {
        int node = tile * 4 + n;
        int base = node * DF;
        zs[n][f] = epsf * h[base + f] + z[base + f];
        __syncthreads();

        float acc = b1f;
        #pragma unroll
        for (int k = 0; k < 64; ++k) acc += zs[n][k] * W1s[k * 64 + f];
        z1s[n][f] = fmaxf(acc, 0.0f);
        __syncthreads();

        float acc2 = b2f;
        #pragma unroll
        for (int k = 0; k < 64; ++k) acc2 += z1s[n][k] * W2s[k * 64 + f];
        float z3 = fmaxf(fmaxf(acc2, 0.0f) + gbf, 0.0f);
        z[base + f] = z3;
        lsum += (double)z3;
        lsq += (double)z3 * (double)z3;
        __syncthreads();
    }

    red[0][n][f] = lsum;
    red[1][n][f] = lsq;
    __syncthreads();
    if (n == 0) {
        double s = red[0][0][f] + red[0][1][f] + red[0][2][f] + red[0][3][f];
        double q = red[1][0][f] + red[1][1][f] + red[1][2][f] + red[1][3][f];
        atomicAdd(&stats[f], s);
        atomicAdd(&stats[64 + f], q);
    }
}

// ---------------------------------------------------------------------------
// Fold BN into per-feature scale/shift: out = z*scale + shift
// ---------------------------------------------------------------------------
__global__ void finalize_kernel(
    const double* __restrict__ stats,
    const float* __restrict__ gamma,
    const float* __restrict__ beta,
    float* __restrict__ scale,
    float* __restrict__ shift)
{
    int f = threadIdx.x;
    double mean = stats[f] * (1.0 / N_NODES);
    double var = stats[64 + f] * (1.0 / N_NODES) - mean * mean;
    double inv = (double)gamma[f] / sqrt(var + 1e-5);
    scale[f] = (float)inv;
    shift[f] = (float)((double)beta[f] - mean * inv);
}

// ---------------------------------------------------------------------------
// Apply BN (scale/shift) + write h + pool into per-graph accumulator
// ---------------------------------------------------------------------------
__global__ __launch_bounds__(256) void bn_pool_kernel(
    const float* __restrict__ z,
    const float* __restrict__ scale,
    const float* __restrict__ shift,
    const int* __restrict__ batch,
    float* __restrict__ hout,
    float* __restrict__ pooled,
    int layerOff)
{
    int idx = blockIdx.x * blockDim.x + threadIdx.x;
    const int total = N_NODES * DF;
    int stride = gridDim.x * blockDim.x;
    for (; idx < total; idx += stride) {
        int node = idx >> 6;
        int f = idx & 63;
        float val = z[idx] * scale[f] + shift[f];
        hout[idx] = val;
        int g = batch[node];
        unsafeAtomicAdd(&pooled[g * LDIM + layerOff + f], val);
    }
}

// ---------------------------------------------------------------------------
// Small dense layer: out[r][c] = (relu?)(b[c] + sum_k in[r][k]*W[k][c])
// grid = NGRAPH blocks, block = LDIM threads
// ---------------------------------------------------------------------------
__global__ __launch_bounds__(192) void proj_kernel(
    const float* __restrict__ in,
    const float* __restrict__ W,
    const float* __restrict__ b,
    float* __restrict__ out,
    int do_relu)
{
    __shared__ float rowS[LDIM];
    int r = blockIdx.x;
    int c = threadIdx.x;
    rowS[c] = in[r * LDIM + c];
    __syncthreads();
    float acc = b[c];
    #pragma unroll 4
    for (int k = 0; k < LDIM; ++k) acc += rowS[k] * W[k * LDIM + c];
    out[r * LDIM + c] = do_relu ? fmaxf(acc, 0.0f) : acc;
}

// ---------------------------------------------------------------------------
extern "C" void kernel_launch(void* const* d_in, const int* in_sizes, int n_in,
                              void* d_out, int out_size, void* d_ws, size_t ws_size,
                              hipStream_t stream)
{
    const float* x        = (const float*)d_in[0];
    const int*   ei       = (const int*)d_in[1];
    const int*   batch    = (const int*)d_in[2];
    const float* W1       = (const float*)d_in[3];
    const float* b1       = (const float*)d_in[4];
    const float* W2       = (const float*)d_in[5];
    const float* b2       = (const float*)d_in[6];
    const float* gin_eps  = (const float*)d_in[7];
    const float* gin_bias = (const float*)d_in[8];
    const float* gamma    = (const float*)d_in[9];
    const float* beta     = (const float*)d_in[10];
    const float* Wp1      = (const float*)d_in[11];
    const float* bp1      = (const float*)d_in[12];
    const float* Wp2      = (const float*)d_in[13];
    const float* bp2      = (const float*)d_in[14];
    float* out = (float*)d_out;

    // workspace layout
    float* agg = (float*)d_ws;                          // N*64
    float* h   = agg + (size_t)N_NODES * DF;            // N*64
    double* stats = (double*)(h + (size_t)N_NODES * DF); // 128 doubles
    float* scale = (float*)(stats + 128);               // 64
    float* shift = scale + 64;                          // 64
    float* pooled = shift + 64;                         // NGRAPH*LDIM
    float* hidden = pooled + (size_t)NGRAPH * LDIM;     // NGRAPH*LDIM

    hipMemsetAsync(pooled, 0, (size_t)NGRAPH * LDIM * sizeof(float), stream);

    const float* hin = x;
    for (int l = 0; l < 3; ++l) {
        hipMemsetAsync(agg, 0, (size_t)N_NODES * DF * sizeof(float), stream);
        hipMemsetAsync(stats, 0, 128 * sizeof(double), stream);

        scatter_kernel<<<(N_EDGES * 64 + 255) / 256, 256, 0, stream>>>(hin, ei, agg);

        mlp_kernel<<<2048, 256, 0, stream>>>(
            hin, agg, W1 + l * 4096, b1 + l * 64, W2 + l * 4096, b2 + l * 64,
            gin_eps + l, gin_bias + l * 64, stats);

        finalize_kernel<<<1, 64, 0, stream>>>(stats, gamma + l * 64, beta + l * 64,
                                              scale, shift);

        bn_pool_kernel<<<2048, 256, 0, stream>>>(agg, scale, shift, batch, h,
                                                 pooled, l * 64);
        hin = h;
    }

    proj_kernel<<<NGRAPH, LDIM, 0, stream>>>(pooled, Wp1, bp1, hidden, 1);
    proj_kernel<<<NGRAPH, LDIM, 0, stream>>>(hidden, Wp2, bp2, out, 0);
}